// Round 1
// baseline (523.589 us; speedup 1.0000x reference)
//
#include <hip/hip_runtime.h>
#include <math.h>

// VQ-VAE vector quantizer for MI355X.
// z: [32, 64, 64, 64] fp32 (B, C=D, H, W), embedding: [1024, 64] fp32.
// Outputs (concatenated fp32 in d_out):
//   [0 .. 8388607]  quantized, layout (b, c, h, w)
//   [8388608]       loss = L + 0.25*L, L = mean((q - z)^2)
//   [8388609]       perplexity
//   [8388610 .. ]   encoding indices (as float), 131072 of them
//
// Numerics strategy: replicate numpy's fp32 arithmetic bit-for-bit where it
// affects argmin ordering (pairwise sums, sequential-FMA dot, op order of
// (zz+ee)-2*dot), since reference distances are quantized at ulp(64).

#define NROWS 131072
#define KCODES 1024
#define DDIM 64

// Prevent fp contraction (hipcc defaults to -ffp-contract=fast which would
// fuse mul+add into fma and change bits vs numpy's separate mul/add).
__device__ __forceinline__ float nofuse(float x) {
    asm("" : "+v"(x));
    return x;
}

// numpy pairwise_sum for n=64 of terms a[i]*a[i] (8-stripe + fixed tree),
// with separate mul-round then add-round per term.
template <typename F>
__device__ __forceinline__ float pairwise64_sq(F load) {
    float r[8];
#pragma unroll
    for (int j = 0; j < 8; j++) {
        float v = load(j);
        r[j] = nofuse(v * v);
    }
#pragma unroll
    for (int i = 8; i < 64; i += 8) {
#pragma unroll
        for (int j = 0; j < 8; j++) {
            float v = load(i + j);
            r[j] = r[j] + nofuse(v * v);
        }
    }
    return ((r[0] + r[1]) + (r[2] + r[3])) + ((r[4] + r[5]) + (r[6] + r[7]));
}

// --- kernel A0: ee[k] = sum(e[k,:]**2) numpy-pairwise ---
__global__ __launch_bounds__(256) void kA0(const float* __restrict__ emb,
                                           float* __restrict__ ee) {
    int k = blockIdx.x * 256 + threadIdx.x;
    if (k >= KCODES) return;
    const float* er = emb + (size_t)k * DDIM;
    ee[k] = pairwise64_sq([&](int i) { return er[i]; });
}

// --- kernel A: per-row argmin over 1024 codes + counts + index output ---
// Block: 256 threads, 64 rows (one (b,h), w=0..63). Thread (rg,kg):
// rows rg*4..+3, cols kg*8..+7 within each 128-code e-tile.
__global__ __launch_bounds__(256) void kA(const float* __restrict__ z,
                                          const float* __restrict__ emb,
                                          const float* __restrict__ ee,
                                          int* __restrict__ counts,
                                          float* __restrict__ out_idx) {
    __shared__ __align__(16) char sm[17408 + 34816 + 256];
    float(*zt)[68] = (float(*)[68])sm;                    // [w][d], padded
    float(*et)[68] = (float(*)[68])(sm + 17408);          // [k][d], padded
    float* zzs = (float*)(sm + 17408 + 34816);
    // reduce buffers alias the e-tile (used only after the k-loop)
    float(*redv)[16] = (float(*)[16])(sm + 17408);
    int(*redi)[16] = (int(*)[16])(sm + 17408 + 4096);

    const int tid = threadIdx.x;
    const int blk = blockIdx.x;       // 0..2047
    const int n0 = blk * 64;
    const int b = blk >> 6;
    const int h = blk & 63;

    // stage z tile: z[((b*64+d)*64+h)*64 + w] -> zt[w][d]; coalesced reads
    const float* zb = z + (size_t)b * 262144 + (size_t)h * 64;
    for (int i = tid; i < 64 * 64; i += 256) {
        int d = i >> 6, w = i & 63;
        zt[w][d] = zb[(size_t)d * 4096 + w];
    }
    __syncthreads();
    if (tid < 64) {
        int w = tid;
        zzs[w] = pairwise64_sq([&](int i) { return zt[w][i]; });
    }

    const int rg = tid & 15, kg = tid >> 4;
    const int r0 = rg * 4, c0 = kg * 8;
    float minv[4] = {INFINITY, INFINITY, INFINITY, INFINITY};
    int mini[4] = {0, 0, 0, 0};

    for (int t = 0; t < 8; t++) {
        const int kbase = t * 128;
        __syncthreads();  // protect et (and zzs on t=0)
        for (int i = tid; i < 128 * 64; i += 256) {
            int k = i >> 6, d = i & 63;
            et[k][d] = emb[(size_t)(kbase + k) * 64 + d];
        }
        __syncthreads();

        float dot[4][8];
#pragma unroll
        for (int r = 0; r < 4; r++)
#pragma unroll
            for (int c = 0; c < 8; c++) dot[r][c] = 0.0f;

#pragma unroll
        for (int dq = 0; dq < 16; dq++) {
            float4 zf[4], ef[8];
#pragma unroll
            for (int r = 0; r < 4; r++)
                zf[r] = *(const float4*)&zt[r0 + r][dq * 4];
#pragma unroll
            for (int c = 0; c < 8; c++)
                ef[c] = *(const float4*)&et[c0 + c][dq * 4];
#pragma unroll
            for (int r = 0; r < 4; r++)
#pragma unroll
                for (int c = 0; c < 8; c++) {
                    // sequential ascending-d FMA chain (matches BLAS sgemm)
                    dot[r][c] = __builtin_fmaf(zf[r].x, ef[c].x, dot[r][c]);
                    dot[r][c] = __builtin_fmaf(zf[r].y, ef[c].y, dot[r][c]);
                    dot[r][c] = __builtin_fmaf(zf[r].z, ef[c].z, dot[r][c]);
                    dot[r][c] = __builtin_fmaf(zf[r].w, ef[c].w, dot[r][c]);
                }
        }

#pragma unroll
        for (int c = 0; c < 8; c++) {
            const int kglob = kbase + c0 + c;
            const float eec = ee[kglob];
#pragma unroll
            for (int r = 0; r < 4; r++) {
                float tt = zzs[r0 + r] + eec;   // fp32 add, rounds at ulp(~64)
                float dv = tt - 2.0f * dot[r][c];  // 2*dot exact; single sub round
                if (dv < minv[r]) { minv[r] = dv; mini[r] = kglob; }
            }
        }
    }
    __syncthreads();  // done reading et; reuse space for reduction
#pragma unroll
    for (int r = 0; r < 4; r++) {
        redv[r0 + r][kg] = minv[r];
        redi[r0 + r][kg] = mini[r];
    }
    __syncthreads();
    if (tid < 64) {
        int w = tid;
        float bv = redv[w][0];
        int bi = redi[w][0];
#pragma unroll
        for (int j = 1; j < 16; j++) {
            float v = redv[w][j];
            int ix = redi[w][j];
            if (v < bv || (v == bv && ix < bi)) { bv = v; bi = ix; }
        }
        out_idx[n0 + w] = (float)bi;
        atomicAdd(&counts[bi], 1);
    }
}

// --- kernel B: gather quantized + fp64 loss accumulation ---
__global__ __launch_bounds__(256) void kB(const float* __restrict__ z,
                                          const float* __restrict__ emb,
                                          const float* __restrict__ out_idxf,
                                          float* __restrict__ out_q,
                                          double* __restrict__ loss_sum) {
    __shared__ int idx_s[64];
    __shared__ double wred[4];
    const int tid = threadIdx.x;
    const int blk = blockIdx.x;
    const int n0 = blk * 64;
    const int b = blk >> 6;
    const int h = blk & 63;
    if (tid < 64) idx_s[tid] = (int)out_idxf[n0 + tid];
    __syncthreads();
    const float* zb = z + (size_t)b * 262144 + (size_t)h * 64;
    float* qb = out_q + (size_t)b * 262144 + (size_t)h * 64;
    double dsum = 0.0;
    for (int i = tid; i < 4096; i += 256) {
        int c = i >> 6, w = i & 63;
        float q = emb[(size_t)idx_s[w] * 64 + c];
        float zv = zb[(size_t)c * 4096 + w];
        qb[(size_t)c * 4096 + w] = q;
        float df = q - zv;
        float s = df * df;
        dsum += (double)s;
    }
    for (int off = 32; off > 0; off >>= 1) dsum += __shfl_down(dsum, off, 64);
    if ((tid & 63) == 0) wred[tid >> 6] = dsum;
    __syncthreads();
    if (tid == 0) {
        double tot = (wred[0] + wred[1]) + (wred[2] + wred[3]);
        atomicAdd(loss_sum, tot);
    }
}

// --- kernel C: loss + perplexity scalars ---
__global__ __launch_bounds__(1024) void kC(const int* __restrict__ counts,
                                           const double* __restrict__ loss_sum,
                                           float* __restrict__ out_loss,
                                           float* __restrict__ out_perp) {
    __shared__ float wr[16];
    const int tid = threadIdx.x;
    float p = (float)counts[tid] * (1.0f / 131072.0f);
    float v = p + 1e-10f;
    float term = p * logf(v);
    float s = term;
    for (int off = 32; off > 0; off >>= 1) s += __shfl_down(s, off, 64);
    if ((tid & 63) == 0) wr[tid >> 6] = s;
    __syncthreads();
    if (tid == 0) {
        float tot = 0.0f;
#pragma unroll
        for (int j = 0; j < 16; j++) tot += wr[j];
        out_perp[0] = expf(-tot);
        double L = *loss_sum / 8388608.0;
        float Lf = (float)L;
        out_loss[0] = Lf + 0.25f * Lf;
    }
}

extern "C" void kernel_launch(void* const* d_in, const int* in_sizes, int n_in,
                              void* d_out, int out_size, void* d_ws, size_t ws_size,
                              hipStream_t stream) {
    const float* z = (const float*)d_in[0];
    const float* emb = (const float*)d_in[1];
    float* out = (float*)d_out;
    float* out_q = out;                    // 8388608
    float* out_loss = out + 8388608;       // 1
    float* out_perp = out + 8388609;       // 1
    float* out_idx = out + 8388610;        // 131072

    char* ws = (char*)d_ws;
    double* loss_sum = (double*)ws;        // 8 B @ 0
    int* counts = (int*)(ws + 64);         // 4 KB @ 64
    float* ee = (float*)(ws + 64 + 4096);  // 4 KB

    hipMemsetAsync(d_ws, 0, 64 + 4096, stream);
    kA0<<<4, 256, 0, stream>>>(emb, ee);
    kA<<<2048, 256, 0, stream>>>(z, emb, ee, counts, out_idx);
    kB<<<2048, 256, 0, stream>>>(z, emb, out_idx, out_q, loss_sum);
    kC<<<1, 1024, 0, stream>>>(counts, loss_sum, out_loss, out_perp);
}

// Round 2
// 322.477 us; speedup vs baseline: 1.6236x; 1.6236x over previous
//
#include <hip/hip_runtime.h>
#include <math.h>

// VQ-VAE vector quantizer for MI355X.
// z: [32, 64, 64, 64] fp32 (B, C=D, H, W), embedding: [1024, 64] fp32.
// Outputs (concatenated fp32 in d_out):
//   [0 .. 8388607]  quantized, layout (b, c, h, w)
//   [8388608]       loss = L + 0.25*L, L = mean((q - z)^2)
//   [8388609]       perplexity
//   [8388610 .. ]   encoding indices (as float), 131072 of them
//
// Numerics strategy: replicate numpy's fp32 arithmetic bit-for-bit where it
// affects argmin ordering (pairwise sums, sequential-FMA dot, op order of
// (zz+ee)-2*dot), since reference distances are quantized at ulp(64).
//
// Round 2: STRIDED thread->tile mapping (rows rg+16r, cols kg+16c) instead of
// blocked (rg*4+r, kg*8+c). Blocked mapping made zf reads stride 272 dwords
// (== 16 mod 32 banks -> 8-way conflict) and ef reads stride 544 (== 0 mod 32
// -> 4-way conflict); rocprof showed 1.76e8 conflict cycles, VALUBusy 37.5%.
// Strided mapping: zf lane stride 68 dwords == +4 banks (2-way alias = free),
// ef kg stride 68 == +4 banks (4 groups on distinct banks, 16-lane broadcast).

#define NROWS 131072
#define KCODES 1024
#define DDIM 64

// Prevent fp contraction (hipcc defaults to -ffp-contract=fast which would
// fuse mul+add into fma and change bits vs numpy's separate mul/add).
__device__ __forceinline__ float nofuse(float x) {
    asm("" : "+v"(x));
    return x;
}

// numpy pairwise_sum for n=64 of terms a[i]*a[i] (8-stripe + fixed tree),
// with separate mul-round then add-round per term.
template <typename F>
__device__ __forceinline__ float pairwise64_sq(F load) {
    float r[8];
#pragma unroll
    for (int j = 0; j < 8; j++) {
        float v = load(j);
        r[j] = nofuse(v * v);
    }
#pragma unroll
    for (int i = 8; i < 64; i += 8) {
#pragma unroll
        for (int j = 0; j < 8; j++) {
            float v = load(i + j);
            r[j] = r[j] + nofuse(v * v);
        }
    }
    return ((r[0] + r[1]) + (r[2] + r[3])) + ((r[4] + r[5]) + (r[6] + r[7]));
}

// --- kernel A0: ee[k] = sum(e[k,:]**2) numpy-pairwise ---
__global__ __launch_bounds__(256) void kA0(const float* __restrict__ emb,
                                           float* __restrict__ ee) {
    int k = blockIdx.x * 256 + threadIdx.x;
    if (k >= KCODES) return;
    const float* er = emb + (size_t)k * DDIM;
    ee[k] = pairwise64_sq([&](int i) { return er[i]; });
}

// --- kernel A: per-row argmin over 1024 codes + counts + index output ---
// Block: 256 threads, 64 rows (one (b,h), w=0..63). Thread (rg,kg):
// rows {rg + 16*r : r<4}, cols {kg + 16*c : c<8} within each 128-code e-tile.
__global__ __launch_bounds__(256) void kA(const float* __restrict__ z,
                                          const float* __restrict__ emb,
                                          const float* __restrict__ ee,
                                          int* __restrict__ counts,
                                          float* __restrict__ out_idx) {
    __shared__ __align__(16) char sm[17408 + 34816 + 256];
    float(*zt)[68] = (float(*)[68])sm;                    // [w][d], padded
    float(*et)[68] = (float(*)[68])(sm + 17408);          // [k][d], padded
    float* zzs = (float*)(sm + 17408 + 34816);
    // reduce buffers alias the e-tile (used only after the k-loop)
    float(*redv)[16] = (float(*)[16])(sm + 17408);
    int(*redi)[16] = (int(*)[16])(sm + 17408 + 4096);

    const int tid = threadIdx.x;
    const int blk = blockIdx.x;       // 0..2047
    const int n0 = blk * 64;
    const int b = blk >> 6;
    const int h = blk & 63;

    // stage z tile: z[((b*64+d)*64+h)*64 + w] -> zt[w][d]; coalesced reads
    const float* zb = z + (size_t)b * 262144 + (size_t)h * 64;
    for (int i = tid; i < 64 * 64; i += 256) {
        int d = i >> 6, w = i & 63;
        zt[w][d] = zb[(size_t)d * 4096 + w];
    }
    __syncthreads();
    if (tid < 64) {
        int w = tid;
        zzs[w] = pairwise64_sq([&](int i) { return zt[w][i]; });
    }

    const int rg = tid & 15, kg = tid >> 4;
    float minv[4] = {INFINITY, INFINITY, INFINITY, INFINITY};
    int mini[4] = {0, 0, 0, 0};

    for (int t = 0; t < 8; t++) {
        const int kbase = t * 128;
        __syncthreads();  // protect et (and zzs on t=0)
        for (int i = tid; i < 128 * 64; i += 256) {
            int k = i >> 6, d = i & 63;
            et[k][d] = emb[(size_t)(kbase + k) * 64 + d];
        }
        __syncthreads();

        float dot[4][8];
#pragma unroll
        for (int r = 0; r < 4; r++)
#pragma unroll
            for (int c = 0; c < 8; c++) dot[r][c] = 0.0f;

#pragma unroll
        for (int dq = 0; dq < 16; dq++) {
            float4 zf[4], ef[8];
#pragma unroll
            for (int r = 0; r < 4; r++)
                zf[r] = *(const float4*)&zt[rg + 16 * r][dq * 4];
#pragma unroll
            for (int c = 0; c < 8; c++)
                ef[c] = *(const float4*)&et[kg + 16 * c][dq * 4];
#pragma unroll
            for (int r = 0; r < 4; r++)
#pragma unroll
                for (int c = 0; c < 8; c++) {
                    // sequential ascending-d FMA chain (matches BLAS sgemm)
                    dot[r][c] = __builtin_fmaf(zf[r].x, ef[c].x, dot[r][c]);
                    dot[r][c] = __builtin_fmaf(zf[r].y, ef[c].y, dot[r][c]);
                    dot[r][c] = __builtin_fmaf(zf[r].z, ef[c].z, dot[r][c]);
                    dot[r][c] = __builtin_fmaf(zf[r].w, ef[c].w, dot[r][c]);
                }
        }

#pragma unroll
        for (int c = 0; c < 8; c++) {
            const int kglob = kbase + kg + 16 * c;
            const float eec = ee[kglob];
#pragma unroll
            for (int r = 0; r < 4; r++) {
                float tt = zzs[rg + 16 * r] + eec;  // fp32 add, rounds at ulp(~64)
                float dv = tt - 2.0f * dot[r][c];   // 2*dot exact; single sub round
                if (dv < minv[r]) { minv[r] = dv; mini[r] = kglob; }
            }
        }
    }
    __syncthreads();  // done reading et; reuse space for reduction
#pragma unroll
    for (int r = 0; r < 4; r++) {
        redv[rg + 16 * r][kg] = minv[r];
        redi[rg + 16 * r][kg] = mini[r];
    }
    __syncthreads();
    if (tid < 64) {
        int w = tid;
        float bv = redv[w][0];
        int bi = redi[w][0];
#pragma unroll
        for (int j = 1; j < 16; j++) {
            float v = redv[w][j];
            int ix = redi[w][j];
            if (v < bv || (v == bv && ix < bi)) { bv = v; bi = ix; }
        }
        out_idx[n0 + w] = (float)bi;
        atomicAdd(&counts[bi], 1);
    }
}

// --- kernel B: gather quantized + fp64 loss accumulation ---
__global__ __launch_bounds__(256) void kB(const float* __restrict__ z,
                                          const float* __restrict__ emb,
                                          const float* __restrict__ out_idxf,
                                          float* __restrict__ out_q,
                                          double* __restrict__ loss_sum) {
    __shared__ int idx_s[64];
    __shared__ double wred[4];
    const int tid = threadIdx.x;
    const int blk = blockIdx.x;
    const int n0 = blk * 64;
    const int b = blk >> 6;
    const int h = blk & 63;
    if (tid < 64) idx_s[tid] = (int)out_idxf[n0 + tid];
    __syncthreads();
    const float* zb = z + (size_t)b * 262144 + (size_t)h * 64;
    float* qb = out_q + (size_t)b * 262144 + (size_t)h * 64;
    double dsum = 0.0;
    for (int i = tid; i < 4096; i += 256) {
        int c = i >> 6, w = i & 63;
        float q = emb[(size_t)idx_s[w] * 64 + c];
        float zv = zb[(size_t)c * 4096 + w];
        qb[(size_t)c * 4096 + w] = q;
        float df = q - zv;
        float s = df * df;
        dsum += (double)s;
    }
    for (int off = 32; off > 0; off >>= 1) dsum += __shfl_down(dsum, off, 64);
    if ((tid & 63) == 0) wred[tid >> 6] = dsum;
    __syncthreads();
    if (tid == 0) {
        double tot = (wred[0] + wred[1]) + (wred[2] + wred[3]);
        atomicAdd(loss_sum, tot);
    }
}

// --- kernel C: loss + perplexity scalars ---
__global__ __launch_bounds__(1024) void kC(const int* __restrict__ counts,
                                           const double* __restrict__ loss_sum,
                                           float* __restrict__ out_loss,
                                           float* __restrict__ out_perp) {
    __shared__ float wr[16];
    const int tid = threadIdx.x;
    float p = (float)counts[tid] * (1.0f / 131072.0f);
    float v = p + 1e-10f;
    float term = p * logf(v);
    float s = term;
    for (int off = 32; off > 0; off >>= 1) s += __shfl_down(s, off, 64);
    if ((tid & 63) == 0) wr[tid >> 6] = s;
    __syncthreads();
    if (tid == 0) {
        float tot = 0.0f;
#pragma unroll
        for (int j = 0; j < 16; j++) tot += wr[j];
        out_perp[0] = expf(-tot);
        double L = *loss_sum / 8388608.0;
        float Lf = (float)L;
        out_loss[0] = Lf + 0.25f * Lf;
    }
}

extern "C" void kernel_launch(void* const* d_in, const int* in_sizes, int n_in,
                              void* d_out, int out_size, void* d_ws, size_t ws_size,
                              hipStream_t stream) {
    const float* z = (const float*)d_in[0];
    const float* emb = (const float*)d_in[1];
    float* out = (float*)d_out;
    float* out_q = out;                    // 8388608
    float* out_loss = out + 8388608;       // 1
    float* out_perp = out + 8388609;       // 1
    float* out_idx = out + 8388610;        // 131072

    char* ws = (char*)d_ws;
    double* loss_sum = (double*)ws;        // 8 B @ 0
    int* counts = (int*)(ws + 64);         // 4 KB @ 64
    float* ee = (float*)(ws + 64 + 4096);  // 4 KB

    hipMemsetAsync(d_ws, 0, 64 + 4096, stream);
    kA0<<<4, 256, 0, stream>>>(emb, ee);
    kA<<<2048, 256, 0, stream>>>(z, emb, ee, counts, out_idx);
    kB<<<2048, 256, 0, stream>>>(z, emb, out_idx, out_q, loss_sum);
    kC<<<1, 1024, 0, stream>>>(counts, loss_sum, out_loss, out_perp);
}

// Round 3
// 276.395 us; speedup vs baseline: 1.8943x; 1.1667x over previous
//
#include <hip/hip_runtime.h>
#include <math.h>

// VQ-VAE vector quantizer for MI355X.
// z: [32, 64, 64, 64] fp32 (B, C=D, H, W), embedding: [1024, 64] fp32.
// Outputs (concatenated fp32 in d_out):
//   [0 .. 8388607]  quantized, layout (b, c, h, w)
//   [8388608]       loss = L + 0.25*L, L = mean((q - z)^2)
//   [8388609]       perplexity
//   [8388610 .. ]   encoding indices (as float), 131072 of them
//
// Numerics: replicate numpy's fp32 arithmetic bit-for-bit where it affects
// argmin ordering (pairwise sums, sequential-FMA dot, op order of
// (zz+ee)-2*dot), since reference distances are quantized at ulp(64).
//
// Round 3: kernel A was LDS-read-throughput-bound (per-CU: 49152 b128 x 12cyc
// = 246us > VALU 109us). Register tile 4x8 -> 8x8 on a 128x128 block tile
// raises FMA/b128 from 10.7 to 16 -> 32768 b128/CU = 164us LDS floor.
// 70KB LDS -> dynamic shared mem + hipFuncSetAttribute (2 blocks/CU).

#define NROWS 131072
#define KCODES 1024
#define DDIM 64

// Prevent fp contraction (hipcc defaults to -ffp-contract=fast which would
// fuse mul+add into fma and change bits vs numpy's separate mul/add).
__device__ __forceinline__ float nofuse(float x) {
    asm("" : "+v"(x));
    return x;
}

// numpy pairwise_sum for n=64 of terms a[i]*a[i] (8-stripe + fixed tree),
// with separate mul-round then add-round per term.
template <typename F>
__device__ __forceinline__ float pairwise64_sq(F load) {
    float r[8];
#pragma unroll
    for (int j = 0; j < 8; j++) {
        float v = load(j);
        r[j] = nofuse(v * v);
    }
#pragma unroll
    for (int i = 8; i < 64; i += 8) {
#pragma unroll
        for (int j = 0; j < 8; j++) {
            float v = load(i + j);
            r[j] = r[j] + nofuse(v * v);
        }
    }
    return ((r[0] + r[1]) + (r[2] + r[3])) + ((r[4] + r[5]) + (r[6] + r[7]));
}

// --- kernel A0: ee[k] = sum(e[k,:]**2) numpy-pairwise ---
__global__ __launch_bounds__(256) void kA0(const float* __restrict__ emb,
                                           float* __restrict__ ee) {
    int k = blockIdx.x * 256 + threadIdx.x;
    if (k >= KCODES) return;
    const float* er = emb + (size_t)k * DDIM;
    ee[k] = pairwise64_sq([&](int i) { return er[i]; });
}

// --- kernel A: per-row argmin over 1024 codes + counts + index output ---
// Block: 256 threads, 128 rows (b fixed, two h values, w contiguous).
// Thread (rg,kg) rg=tid&15, kg=tid>>4: rows {rg+16r: r<8},
// cols {kg+16c: c<8} within each 128-code e-tile. 8x8 register tile.
// LDS (dynamic, 70144 B):
//   zt   @0      : [128][68] fp32  (34816 B)   row-padded +4 dwords
//   et   @34816  : [128][68] fp32  (34816 B)
//   zzs  @69632  : [128] fp32      (512 B)
//   redv @34816  : [128][16] fp32  (aliases et, used after k-loop)
//   redi @43008  : [128][16] int
__global__ __launch_bounds__(256, 2) void kA(const float* __restrict__ z,
                                             const float* __restrict__ emb,
                                             const float* __restrict__ ee,
                                             int* __restrict__ counts,
                                             float* __restrict__ out_idx) {
    extern __shared__ __align__(16) char sm[];
    float(*zt)[68] = (float(*)[68])sm;
    float(*et)[68] = (float(*)[68])(sm + 34816);
    float* zzs = (float*)(sm + 69632);
    float(*redv)[16] = (float(*)[16])(sm + 34816);
    int(*redi)[16] = (int(*)[16])(sm + 43008);

    const int tid = threadIdx.x;
    const int blk = blockIdx.x;       // 0..1023
    const int n0 = blk * 128;
    const int b = blk >> 5;
    const int h0 = (blk & 31) * 2;

    // stage z tile: rows j=0..127 are (h0,h0+1) x w; z[b][d][h0..][w] is
    // contiguous over j for fixed d -> coalesced.
    const float* zb = z + (size_t)b * 262144 + (size_t)h0 * 64;
    for (int i = tid; i < 128 * 64; i += 256) {
        int d = i >> 7, j = i & 127;
        zt[j][d] = zb[(size_t)d * 4096 + j];
    }
    __syncthreads();
    if (tid < 128) {
        int w = tid;
        zzs[w] = pairwise64_sq([&](int i) { return zt[w][i]; });
    }
    __syncthreads();

    const int rg = tid & 15, kg = tid >> 4;
    float zzr[8];
#pragma unroll
    for (int r = 0; r < 8; r++) zzr[r] = zzs[rg + 16 * r];

    float minv[8];
    int mini[8];
#pragma unroll
    for (int r = 0; r < 8; r++) { minv[r] = INFINITY; mini[r] = 0; }

    for (int t = 0; t < 8; t++) {
        const int kbase = t * 128;
        __syncthreads();  // protect et from previous iteration's readers
        // stage e tile with float4: 2048 float4 / 256 threads = 8 each
        for (int i = tid; i < 128 * 16; i += 256) {
            int k = i >> 4, q = i & 15;
            *(float4*)&et[k][q * 4] =
                *(const float4*)&emb[(size_t)(kbase + k) * 64 + q * 4];
        }
        __syncthreads();

        float dot[8][8];
#pragma unroll
        for (int r = 0; r < 8; r++)
#pragma unroll
            for (int c = 0; c < 8; c++) dot[r][c] = 0.0f;

#pragma unroll 4
        for (int dq = 0; dq < 16; dq++) {
            float4 zf[8], ef[8];
#pragma unroll
            for (int r = 0; r < 8; r++)
                zf[r] = *(const float4*)&zt[rg + 16 * r][dq * 4];
#pragma unroll
            for (int c = 0; c < 8; c++)
                ef[c] = *(const float4*)&et[kg + 16 * c][dq * 4];
#pragma unroll
            for (int r = 0; r < 8; r++)
#pragma unroll
                for (int c = 0; c < 8; c++) {
                    // sequential ascending-d FMA chain (matches BLAS sgemm)
                    dot[r][c] = __builtin_fmaf(zf[r].x, ef[c].x, dot[r][c]);
                    dot[r][c] = __builtin_fmaf(zf[r].y, ef[c].y, dot[r][c]);
                    dot[r][c] = __builtin_fmaf(zf[r].z, ef[c].z, dot[r][c]);
                    dot[r][c] = __builtin_fmaf(zf[r].w, ef[c].w, dot[r][c]);
                }
        }

#pragma unroll
        for (int c = 0; c < 8; c++) {
            const int kglob = kbase + kg + 16 * c;
            const float eec = ee[kglob];
#pragma unroll
            for (int r = 0; r < 8; r++) {
                float tt = zzr[r] + eec;           // rounds at ulp(~64)
                float dv = tt - 2.0f * dot[r][c];  // 2*dot exact; one sub round
                if (dv < minv[r]) { minv[r] = dv; mini[r] = kglob; }
            }
        }
    }
    __syncthreads();  // done reading et; reuse space for reduction
#pragma unroll
    for (int r = 0; r < 8; r++) {
        redv[rg + 16 * r][kg] = minv[r];
        redi[rg + 16 * r][kg] = mini[r];
    }
    __syncthreads();
    if (tid < 128) {
        int w = tid;
        float bv = redv[w][0];
        int bi = redi[w][0];
#pragma unroll
        for (int j = 1; j < 16; j++) {
            float v = redv[w][j];
            int ix = redi[w][j];
            if (v < bv || (v == bv && ix < bi)) { bv = v; bi = ix; }
        }
        out_idx[n0 + w] = (float)bi;
        atomicAdd(&counts[bi], 1);
    }
}

// --- kernel B: gather quantized + fp64 loss accumulation ---
__global__ __launch_bounds__(256) void kB(const float* __restrict__ z,
                                          const float* __restrict__ emb,
                                          const float* __restrict__ out_idxf,
                                          float* __restrict__ out_q,
                                          double* __restrict__ loss_sum) {
    __shared__ int idx_s[64];
    __shared__ double wred[4];
    const int tid = threadIdx.x;
    const int blk = blockIdx.x;
    const int n0 = blk * 64;
    const int b = blk >> 6;
    const int h = blk & 63;
    if (tid < 64) idx_s[tid] = (int)out_idxf[n0 + tid];
    __syncthreads();
    const float* zb = z + (size_t)b * 262144 + (size_t)h * 64;
    float* qb = out_q + (size_t)b * 262144 + (size_t)h * 64;
    double dsum = 0.0;
    for (int i = tid; i < 4096; i += 256) {
        int c = i >> 6, w = i & 63;
        float q = emb[(size_t)idx_s[w] * 64 + c];
        float zv = zb[(size_t)c * 4096 + w];
        qb[(size_t)c * 4096 + w] = q;
        float df = q - zv;
        float s = df * df;
        dsum += (double)s;
    }
    for (int off = 32; off > 0; off >>= 1) dsum += __shfl_down(dsum, off, 64);
    if ((tid & 63) == 0) wred[tid >> 6] = dsum;
    __syncthreads();
    if (tid == 0) {
        double tot = (wred[0] + wred[1]) + (wred[2] + wred[3]);
        atomicAdd(loss_sum, tot);
    }
}

// --- kernel C: loss + perplexity scalars ---
__global__ __launch_bounds__(1024) void kC(const int* __restrict__ counts,
                                           const double* __restrict__ loss_sum,
                                           float* __restrict__ out_loss,
                                           float* __restrict__ out_perp) {
    __shared__ float wr[16];
    const int tid = threadIdx.x;
    float p = (float)counts[tid] * (1.0f / 131072.0f);
    float v = p + 1e-10f;
    float term = p * logf(v);
    float s = term;
    for (int off = 32; off > 0; off >>= 1) s += __shfl_down(s, off, 64);
    if ((tid & 63) == 0) wr[tid >> 6] = s;
    __syncthreads();
    if (tid == 0) {
        float tot = 0.0f;
#pragma unroll
        for (int j = 0; j < 16; j++) tot += wr[j];
        out_perp[0] = expf(-tot);
        double L = *loss_sum / 8388608.0;
        float Lf = (float)L;
        out_loss[0] = Lf + 0.25f * Lf;
    }
}

extern "C" void kernel_launch(void* const* d_in, const int* in_sizes, int n_in,
                              void* d_out, int out_size, void* d_ws, size_t ws_size,
                              hipStream_t stream) {
    const float* z = (const float*)d_in[0];
    const float* emb = (const float*)d_in[1];
    float* out = (float*)d_out;
    float* out_q = out;                    // 8388608
    float* out_loss = out + 8388608;       // 1
    float* out_perp = out + 8388609;       // 1
    float* out_idx = out + 8388610;        // 131072

    char* ws = (char*)d_ws;
    double* loss_sum = (double*)ws;        // 8 B @ 0
    int* counts = (int*)(ws + 64);         // 4 KB @ 64
    float* ee = (float*)(ws + 64 + 4096);  // 4 KB

    // Allow 70144 B dynamic LDS for kA (host-side attribute set; not a
    // stream op, so graph-capture-safe; idempotent and deterministic).
    (void)hipFuncSetAttribute((const void*)kA,
                              hipFuncAttributeMaxDynamicSharedMemorySize,
                              70144);

    hipMemsetAsync(d_ws, 0, 64 + 4096, stream);
    kA0<<<4, 256, 0, stream>>>(emb, ee);
    kA<<<1024, 256, 70144, stream>>>(z, emb, ee, counts, out_idx);
    kB<<<2048, 256, 0, stream>>>(z, emb, out_idx, out_q, loss_sum);
    kC<<<1, 1024, 0, stream>>>(counts, loss_sum, out_loss, out_perp);
}